// Round 8
// baseline (192.699 us; speedup 1.0000x reference)
//
#include <hip/hip_runtime.h>
#include <math.h>

typedef _Float16 f16;
typedef __attribute__((ext_vector_type(8))) _Float16 f16x8;
typedef __attribute__((ext_vector_type(4))) _Float16 f16x4;
typedef __attribute__((ext_vector_type(4))) float f32x4;
typedef __attribute__((ext_vector_type(16))) float f32x16;

#define MFMA16(a, b, c) __builtin_amdgcn_mfma_f32_16x16x32_f16((a), (b), (c), 0, 0, 0)
#define MFMA32(a, b, c) __builtin_amdgcn_mfma_f32_32x32x16_f16((a), (b), (c), 0, 0, 0)

__device__ __forceinline__ void gld16(const f16* g, f16* l) {
  __builtin_amdgcn_global_load_lds(
      (const __attribute__((address_space(1))) unsigned int*)g,
      (__attribute__((address_space(3))) unsigned int*)l, 16, 0, 0);
}

__device__ __forceinline__ f16x8 pack8(const float* src) {
  float4 f0 = *(const float4*)src;
  float4 f1 = *(const float4*)(src + 4);
  f16x8 v;
  v[0] = (f16)f0.x; v[1] = (f16)f0.y; v[2] = (f16)f0.z; v[3] = (f16)f0.w;
  v[4] = (f16)f1.x; v[5] = (f16)f1.y; v[6] = (f16)f1.z; v[7] = (f16)f1.w;
  return v;
}

// ---------------- prep: ew = exp(wbias) as f16 [4096][4096] ----------------
__global__ __launch_bounds__(256) void prep_ew(const float* __restrict__ wb,
                                               f16* __restrict__ ew) {
  const size_t stride = (size_t)gridDim.x * 256;
  const size_t total = (size_t)4096 * 4096 / 4;
  for (size_t i = (size_t)blockIdx.x * 256 + threadIdx.x; i < total; i += stride) {
    float4 f = ((const float4*)wb)[i];
    f16x4 o;
    o.x = (f16)expf(f.x); o.y = (f16)expf(f.y);
    o.z = (f16)expf(f.z); o.w = (f16)expf(f.w);
    ((f16x4*)ew)[i] = o;
  }
}

// ---------------- prep: cast weights to f16 ----------------
__global__ __launch_bounds__(256) void prep_w(const float* __restrict__ wq,
                                              const float* __restrict__ wk,
                                              const float* __restrict__ wv,
                                              const float* __restrict__ wp,
                                              f16* __restrict__ wqkvb,
                                              f16* __restrict__ wpb) {
  int i = blockIdx.x * 256 + threadIdx.x;  // grid = 128 -> i in [0, 32768)
  wqkvb[i] = (f16)wk[i];
  wqkvb[32768 + i] = (f16)wv[i];
  wqkvb[65536 + i] = (f16)wq[i];
  wpb[i] = (f16)wp[i];
}

// ---------------- k1_qkv: sigQ[m][h], XT[b*128+h][t]=eK*V, XT[b*128+64+h][t]=eK --------
__global__ __launch_bounds__(256) void k1_qkv(const float* __restrict__ x,
                                              const f16* __restrict__ wqkvb,
                                              const float* __restrict__ bq,
                                              const float* __restrict__ bk,
                                              const float* __restrict__ bv,
                                              f16* __restrict__ sigQ,
                                              f16* __restrict__ XT) {
  __shared__ alignas(16) f16 sW[192 * 64];
  __shared__ alignas(16) f16 sX[64 * 64];
  const int tid = threadIdx.x;
  const int wave = tid >> 6, lane = tid & 63;
  const int m0 = blockIdx.x * 64;
  const int l15 = lane & 15;

  f32x4 accQ[4], accK[4], accV[4];
#pragma unroll
  for (int j = 0; j < 4; ++j) {
    accQ[j] = (f32x4){0.f, 0.f, 0.f, 0.f};
    accK[j] = (f32x4){0.f, 0.f, 0.f, 0.f};
    accV[j] = (f32x4){0.f, 0.f, 0.f, 0.f};
  }

  const int sc8 = tid & 7;
  const int wr8 = (tid >> 3) & 7;
  const int wcol = (sc8 ^ wr8) * 8;

  for (int ks = 0; ks < 512; ks += 64) {
#pragma unroll
    for (int q = 0; q < 6; ++q) {
      int r = q * 32 + (tid >> 3);
      gld16(wqkvb + (size_t)r * 512 + ks + wcol, &sW[r * 64 + sc8 * 8]);
    }
#pragma unroll
    for (int u = 0; u < 2; ++u) {
      int un = tid + u * 256;
      int r = un >> 3, c8 = un & 7;
      *(f16x8*)&sX[r * 64 + ((c8 ^ (r & 7)) * 8)] =
          pack8(x + (size_t)(m0 + r) * 512 + ks + c8 * 8);
    }
    __syncthreads();
#pragma unroll
    for (int kk = 0; kk < 2; ++kk) {
      const int c = kk * 4 + (lane >> 4);
      const int rK = wave * 16 + l15;
      const int rV = 64 + rK;
      f16x8 aK = *(const f16x8*)&sW[rK * 64 + ((c ^ (rK & 7)) * 8)];
      f16x8 aV = *(const f16x8*)&sW[rV * 64 + ((c ^ (rV & 7)) * 8)];
      f16x8 aQ = *(const f16x8*)&sX[rK * 64 + ((c ^ (rK & 7)) * 8)];
#pragma unroll
      for (int j = 0; j < 4; ++j) {
        const int rX = j * 16 + l15;
        const int rWq = 128 + j * 16 + l15;
        f16x8 bx = *(const f16x8*)&sX[rX * 64 + ((c ^ (rX & 7)) * 8)];
        f16x8 bw = *(const f16x8*)&sW[rWq * 64 + ((c ^ (rWq & 7)) * 8)];
        accK[j] = MFMA16(aK, bx, accK[j]);
        accV[j] = MFMA16(aV, bx, accV[j]);
        accQ[j] = MFMA16(aQ, bw, accQ[j]);
      }
    }
    __syncthreads();
  }
  const int b = m0 >> 12, t0 = m0 & 4095;
#pragma unroll
  for (int j = 0; j < 4; ++j) {
    const int h = j * 16 + l15;
    const float bqv = bq[h];
#pragma unroll
    for (int r = 0; r < 4; ++r) {
      const int m = m0 + wave * 16 + (lane >> 4) * 4 + r;
      const float v = accQ[j][r] + bqv;
      sigQ[(size_t)m * 64 + h] = (f16)(1.f / (1.f + expf(-v)));
    }
  }
#pragma unroll
  for (int r = 0; r < 4; ++r) {
    const int h = wave * 16 + (lane >> 4) * 4 + r;
    const float bkv = bk[h], bvv = bv[h];
    const size_t rowKV = (size_t)(b * 128 + h) * 4096;
    const size_t rowK = (size_t)(b * 128 + 64 + h) * 4096;
#pragma unroll
    for (int j = 0; j < 4; ++j) {
      const int t = t0 + j * 16 + l15;
      const float ek = expf(accK[j][r] + bkv);
      const float ev = accV[j][r] + bvv;
      XT[rowKV + t] = (f16)(ek * ev);
      XT[rowK + t] = (f16)ek;
    }
  }
}

// ---------------- k2_big: Yt = sigQ * (ew@num^T)/(ew@den^T), fused ----------------
// BM=128, BN=128 (64 num + 64 den of one batch), BK=64, 512 thr, 8 waves.
// A (ew) triple-buffered in LDS via gld16 (3 x 16KB); B (XT) loaded DIRECTLY
// global->VGPR per wave (XT is [col][k] row-major => B-frag = 4 plain f16x8
// loads per pointer), double-buffered in registers (bcur/bnxt, static names).
// ONE raw s_barrier + ONE counted vmcnt(8) per K-tile; no lgkmcnt drain (own
// ds_reads retire via MFMA data dependency before the barrier; gld16 counts
// on vmcnt). No K-split -> no merge; epilogue straight from regs.
// XOR-16 A swizzle (R7-verified 0-conflict pattern); XCD map: same-m blocks
// on one XCD.
__global__ __launch_bounds__(512) void k2_big(const f16* __restrict__ A,
                                              const f16* __restrict__ Bm,
                                              const f16* __restrict__ sigQ,
                                              f16* __restrict__ Yt) {
  __shared__ alignas(16) f16 sA[3 * 8192];  // 3 bufs x [64][128] packed (16KB each)
  const int tid = threadIdx.x;
  const int wave = tid >> 6, lane = tid & 63;
  const int wr = wave >> 1;   // row strip 0..3 (32 rows each)
  const int wc = wave & 1;    // col half 0..1 (32 num + 32 den cols)
  const int bid = blockIdx.x;
  const int b = (bid >> 3) & 7;
  const int m0 = ((bid & 7) + 8 * (bid >> 6)) * 128;  // same-m blocks share XCD

  const int l31 = lane & 31, l15 = lane & 15, lhi = lane >> 5;

  // A staging map (pre-swizzled source, linear LDS dest): d = q*512+tid
  int aRow[2], aCol[2];
#pragma unroll
  for (int q = 0; q < 2; ++q) {
    int d = q * 512 + tid;
    int lrow = d >> 4, cc = d & 15;
    int oc = cc ^ (lrow & 15);
    aRow[q] = lrow + 64 * (oc >> 3);
    aCol[q] = (oc & 7) * 8;
  }

  // B per-wave direct pointers: num rows b*128 + wc*32 + l31, den +64
  const f16* bp0 = Bm + ((size_t)(b * 128 + wc * 32 + l31)) * 4096 + lhi * 8;
  const f16* bp1 = bp0 + (size_t)64 * 4096;

  const int arow128 = ((wr & 1) * 32 + l31) * 128;
  const int wrh8 = (wr >> 1) * 8;

  f32x16 accN, accD;
#pragma unroll
  for (int r = 0; r < 16; ++r) { accN[r] = 0.f; accD[r] = 0.f; }

  f16x8 bcur[8], bnxt[8];

#define K2_STAGEA(off, ks)                                                      \
  do {                                                                          \
    _Pragma("unroll") for (int q = 0; q < 2; ++q)                               \
        gld16(A + (size_t)(m0 + aRow[q]) * 4096 + (ks) + aCol[q],               \
              &sA[(off) + (q * 512 + tid) * 8]);                                \
  } while (0)

#define K2_LOADB(dst, T)                                                        \
  do {                                                                          \
    const f16* p0 = bp0 + (size_t)(T) * 64;                                     \
    const f16* p1 = bp1 + (size_t)(T) * 64;                                     \
    _Pragma("unroll") for (int kk = 0; kk < 4; ++kk) {                          \
      dst[2 * kk] = *(const f16x8*)(p0 + kk * 16);                              \
      dst[2 * kk + 1] = *(const f16x8*)(p1 + kk * 16);                          \
    }                                                                           \
  } while (0)

#define K2_COMPUTE(bin)                                                         \
  do {                                                                          \
    const f16* pA = &sA[bufoff];                                                \
    __builtin_amdgcn_s_setprio(1);                                              \
    _Pragma("unroll") for (int kk = 0; kk < 4; ++kk) {                          \
      const int c = kk * 2 + lhi;                                               \
      f16x8 af = *(const f16x8*)&pA[arow128 + (((wrh8 + c) ^ l15) * 8)];        \
      accN = MFMA32(af, bin[2 * kk], accN);                                     \
      accD = MFMA32(af, bin[2 * kk + 1], accD);                                 \
    }                                                                           \
    __builtin_amdgcn_s_setprio(0);                                              \
    bufoff += 8192; if (bufoff == 24576) bufoff = 0;                            \
    stageoff += 8192; if (stageoff == 24576) stageoff = 0;                      \
  } while (0)

// full body: load B(T+1), counted wait, barrier, stage A(T+2), compute T
#define K2_BODY_FULL(T, bin, bout)                                              \
  do {                                                                          \
    K2_LOADB(bout, (T) + 1);                                                    \
    asm volatile("s_waitcnt vmcnt(8)" ::: "memory");                            \
    __builtin_amdgcn_sched_barrier(0);                                          \
    __builtin_amdgcn_s_barrier();                                               \
    __builtin_amdgcn_sched_barrier(0);                                          \
    K2_STAGEA(stageoff, ((T) + 2) * 64);                                        \
    K2_COMPUTE(bin);                                                            \
  } while (0)

  // prologue: A(0)->buf0, A(1)->buf1, B(0)->bcur
  K2_STAGEA(0, 0);
  K2_STAGEA(8192, 64);
  K2_LOADB(bcur, 0);
  int bufoff = 0, stageoff = 16384;

  const int nk = 64;
  for (int t = 0; t < nk - 2; t += 2) {
    K2_BODY_FULL(t, bcur, bnxt);
    K2_BODY_FULL(t + 1, bnxt, bcur);
  }
  // t = 62: load B(63), no stage
  K2_LOADB(bnxt, 63);
  asm volatile("s_waitcnt vmcnt(8)" ::: "memory");
  __builtin_amdgcn_sched_barrier(0);
  __builtin_amdgcn_s_barrier();
  __builtin_amdgcn_sched_barrier(0);
  K2_COMPUTE(bcur);
  // t = 63: nothing in flight
  asm volatile("s_waitcnt vmcnt(0)" ::: "memory");
  __builtin_amdgcn_sched_barrier(0);
  __builtin_amdgcn_s_barrier();
  __builtin_amdgcn_sched_barrier(0);
  K2_COMPUTE(bnxt);
#undef K2_BODY_FULL
#undef K2_COMPUTE
#undef K2_LOADB
#undef K2_STAGEA

  // fused epilogue straight from registers: Yt = sigQ * num / den
  const int h = wc * 32 + l31;
#pragma unroll
  for (int r = 0; r < 16; ++r) {
    const int trow = m0 + wr * 32 + (r & 3) + 8 * (r >> 2) + 4 * lhi;
    const size_t mrow = (size_t)b * 4096 + trow;
    const float sq = (float)sigQ[mrow * 64 + h];
    Yt[mrow * 64 + h] = (f16)(sq * accN[r] / accD[r]);
  }
}

// ---------------- k4_out: out[m][d] = Yt @ wp^T + bp (f32 out) ----------------
__global__ __launch_bounds__(256) void k4_out(const f16* __restrict__ Yt,
                                              const f16* __restrict__ wpb,
                                              const float* __restrict__ bp,
                                              float* __restrict__ out) {
  __shared__ alignas(16) f16 sA[128 * 64];
  __shared__ alignas(16) f16 sB[128 * 64];
  const int tid = threadIdx.x;
  const int wave = tid >> 6, lane = tid & 63;
  const int m0 = blockIdx.x * 128;  // 256
  const int n0 = blockIdx.y * 128;  // 4
  const int wm = (wave >> 1) * 64;
  const int wn = (wave & 1) * 64;
  const int l15 = lane & 15;
  const int sc8 = tid & 7;
  const int scol = (sc8 ^ ((tid >> 3) & 7)) * 8;

#pragma unroll
  for (int q = 0; q < 4; ++q) {
    int r = q * 32 + (tid >> 3);
    gld16(Yt + (size_t)(m0 + r) * 64 + scol, &sA[r * 64 + sc8 * 8]);
    gld16(wpb + (size_t)(n0 + r) * 64 + scol, &sB[r * 64 + sc8 * 8]);
  }
  __syncthreads();

  f32x4 acc[4][4];
#pragma unroll
  for (int i = 0; i < 4; ++i)
#pragma unroll
    for (int j = 0; j < 4; ++j) acc[i][j] = (f32x4){0.f, 0.f, 0.f, 0.f};

#pragma unroll
  for (int kk = 0; kk < 2; ++kk) {
    const int c = kk * 4 + (lane >> 4);
    f16x8 af[4], bfr[4];
#pragma unroll
    for (int i = 0; i < 4; ++i) {
      const int r = wm + i * 16 + l15;
      af[i] = *(const f16x8*)&sA[r * 64 + ((c ^ (r & 7)) * 8)];
    }
#pragma unroll
    for (int j = 0; j < 4; ++j) {
      const int r = wn + j * 16 + l15;
      bfr[j] = *(const f16x8*)&sB[r * 64 + ((c ^ (r & 7)) * 8)];
    }
#pragma unroll
    for (int i = 0; i < 4; ++i)
#pragma unroll
      for (int j = 0; j < 4; ++j) acc[i][j] = MFMA16(af[i], bfr[j], acc[i][j]);
  }

#pragma unroll
  for (int i = 0; i < 4; ++i) {
    const int row = m0 + wm + i * 16 + (lane >> 4) * 4;
#pragma unroll
    for (int j = 0; j < 4; ++j) {
      const int col = n0 + wn + j * 16 + l15;
      const float bpv = bp[col];
#pragma unroll
      for (int r = 0; r < 4; ++r)
        out[(size_t)(row + r) * 512 + col] = acc[i][j][r] + bpv;
    }
  }
}

extern "C" void kernel_launch(void* const* d_in, const int* in_sizes, int n_in,
                              void* d_out, int out_size, void* d_ws, size_t ws_size,
                              hipStream_t stream) {
  const float* x = (const float*)d_in[0];
  const float* wq = (const float*)d_in[1];
  const float* bq = (const float*)d_in[2];
  const float* wk = (const float*)d_in[3];
  const float* bk = (const float*)d_in[4];
  const float* wv = (const float*)d_in[5];
  const float* bv = (const float*)d_in[6];
  const float* wp = (const float*)d_in[7];
  const float* bp = (const float*)d_in[8];
  const float* wbias = (const float*)d_in[9];
  float* out = (float*)d_out;

  char* ws = (char*)d_ws;
  f16* ew = (f16*)(ws);                  // 33,554,432 B
  f16* XT = (f16*)(ws + 33554432);       //  8,388,608 B
  f16* sigQ = (f16*)(ws + 41943040);     //  4,194,304 B
  f16* Yt = (f16*)(ws + 46137344);       //  4,194,304 B
  f16* wqkvb = (f16*)(ws + 50331648);    //    196,608 B
  f16* wpb = (f16*)(ws + 50528256);      //     65,536 B (end 50,593,792)

  prep_ew<<<4096, 256, 0, stream>>>(wbias, ew);
  prep_w<<<128, 256, 0, stream>>>(wq, wk, wv, wp, wqkvb, wpb);
  k1_qkv<<<512, 256, 0, stream>>>(x, wqkvb, bq, bk, bv, sigQ, XT);
  k2_big<<<256, 512, 0, stream>>>(ew, XT, sigQ, Yt);
  k4_out<<<dim3(256, 4), 256, 0, stream>>>(Yt, wpb, bp, out);
}

// Round 9
// 106.139 us; speedup vs baseline: 1.8155x; 1.8155x over previous
//
#include <hip/hip_runtime.h>
#include <math.h>

typedef _Float16 f16;
typedef __attribute__((ext_vector_type(8))) _Float16 f16x8;
typedef __attribute__((ext_vector_type(4))) _Float16 f16x4;
typedef __attribute__((ext_vector_type(4))) float f32x4;
typedef __attribute__((ext_vector_type(16))) float f32x16;

#define MFMA16(a, b, c) __builtin_amdgcn_mfma_f32_16x16x32_f16((a), (b), (c), 0, 0, 0)
#define MFMA32(a, b, c) __builtin_amdgcn_mfma_f32_32x32x16_f16((a), (b), (c), 0, 0, 0)

__device__ __forceinline__ void gld16(const f16* g, f16* l) {
  __builtin_amdgcn_global_load_lds(
      (const __attribute__((address_space(1))) unsigned int*)g,
      (__attribute__((address_space(3))) unsigned int*)l, 16, 0, 0);
}

__device__ __forceinline__ f16x8 pack8(const float* src) {
  float4 f0 = *(const float4*)src;
  float4 f1 = *(const float4*)(src + 4);
  f16x8 v;
  v[0] = (f16)f0.x; v[1] = (f16)f0.y; v[2] = (f16)f0.z; v[3] = (f16)f0.w;
  v[4] = (f16)f1.x; v[5] = (f16)f1.y; v[6] = (f16)f1.z; v[7] = (f16)f1.w;
  return v;
}

// ---------------- prep: ew = exp(wbias) as f16 [4096][4096] ----------------
__global__ __launch_bounds__(256) void prep_ew(const float* __restrict__ wb,
                                               f16* __restrict__ ew) {
  const size_t stride = (size_t)gridDim.x * 256;
  const size_t total = (size_t)4096 * 4096 / 4;
  for (size_t i = (size_t)blockIdx.x * 256 + threadIdx.x; i < total; i += stride) {
    float4 f = ((const float4*)wb)[i];
    f16x4 o;
    o.x = (f16)expf(f.x); o.y = (f16)expf(f.y);
    o.z = (f16)expf(f.z); o.w = (f16)expf(f.w);
    ((f16x4*)ew)[i] = o;
  }
}

// ---------------- prep: cast weights to f16 ----------------
__global__ __launch_bounds__(256) void prep_w(const float* __restrict__ wq,
                                              const float* __restrict__ wk,
                                              const float* __restrict__ wv,
                                              const float* __restrict__ wp,
                                              f16* __restrict__ wqkvb,
                                              f16* __restrict__ wpb) {
  int i = blockIdx.x * 256 + threadIdx.x;  // grid = 128 -> i in [0, 32768)
  wqkvb[i] = (f16)wk[i];
  wqkvb[32768 + i] = (f16)wv[i];
  wqkvb[65536 + i] = (f16)wq[i];
  wpb[i] = (f16)wp[i];
}

// ---------------- k1_qkv: sigQ[m][h], XT[b*128+h][t]=eK*V, XT[b*128+64+h][t]=eK --------
__global__ __launch_bounds__(256) void k1_qkv(const float* __restrict__ x,
                                              const f16* __restrict__ wqkvb,
                                              const float* __restrict__ bq,
                                              const float* __restrict__ bk,
                                              const float* __restrict__ bv,
                                              f16* __restrict__ sigQ,
                                              f16* __restrict__ XT) {
  __shared__ alignas(16) f16 sW[192 * 64];
  __shared__ alignas(16) f16 sX[64 * 64];
  const int tid = threadIdx.x;
  const int wave = tid >> 6, lane = tid & 63;
  const int m0 = blockIdx.x * 64;
  const int l15 = lane & 15;

  f32x4 accQ[4], accK[4], accV[4];
#pragma unroll
  for (int j = 0; j < 4; ++j) {
    accQ[j] = (f32x4){0.f, 0.f, 0.f, 0.f};
    accK[j] = (f32x4){0.f, 0.f, 0.f, 0.f};
    accV[j] = (f32x4){0.f, 0.f, 0.f, 0.f};
  }

  const int sc8 = tid & 7;
  const int wr8 = (tid >> 3) & 7;
  const int wcol = (sc8 ^ wr8) * 8;

  for (int ks = 0; ks < 512; ks += 64) {
#pragma unroll
    for (int q = 0; q < 6; ++q) {
      int r = q * 32 + (tid >> 3);
      gld16(wqkvb + (size_t)r * 512 + ks + wcol, &sW[r * 64 + sc8 * 8]);
    }
#pragma unroll
    for (int u = 0; u < 2; ++u) {
      int un = tid + u * 256;
      int r = un >> 3, c8 = un & 7;
      *(f16x8*)&sX[r * 64 + ((c8 ^ (r & 7)) * 8)] =
          pack8(x + (size_t)(m0 + r) * 512 + ks + c8 * 8);
    }
    __syncthreads();
#pragma unroll
    for (int kk = 0; kk < 2; ++kk) {
      const int c = kk * 4 + (lane >> 4);
      const int rK = wave * 16 + l15;
      const int rV = 64 + rK;
      f16x8 aK = *(const f16x8*)&sW[rK * 64 + ((c ^ (rK & 7)) * 8)];
      f16x8 aV = *(const f16x8*)&sW[rV * 64 + ((c ^ (rV & 7)) * 8)];
      f16x8 aQ = *(const f16x8*)&sX[rK * 64 + ((c ^ (rK & 7)) * 8)];
#pragma unroll
      for (int j = 0; j < 4; ++j) {
        const int rX = j * 16 + l15;
        const int rWq = 128 + j * 16 + l15;
        f16x8 bx = *(const f16x8*)&sX[rX * 64 + ((c ^ (rX & 7)) * 8)];
        f16x8 bw = *(const f16x8*)&sW[rWq * 64 + ((c ^ (rWq & 7)) * 8)];
        accK[j] = MFMA16(aK, bx, accK[j]);
        accV[j] = MFMA16(aV, bx, accV[j]);
        accQ[j] = MFMA16(aQ, bw, accQ[j]);
      }
    }
    __syncthreads();
  }
  const int b = m0 >> 12, t0 = m0 & 4095;
#pragma unroll
  for (int j = 0; j < 4; ++j) {
    const int h = j * 16 + l15;
    const float bqv = bq[h];
#pragma unroll
    for (int r = 0; r < 4; ++r) {
      const int m = m0 + wave * 16 + (lane >> 4) * 4 + r;
      const float v = accQ[j][r] + bqv;
      sigQ[(size_t)m * 64 + h] = (f16)(1.f / (1.f + expf(-v)));
    }
  }
#pragma unroll
  for (int r = 0; r < 4; ++r) {
    const int h = wave * 16 + (lane >> 4) * 4 + r;
    const float bkv = bk[h], bvv = bv[h];
    const size_t rowKV = (size_t)(b * 128 + h) * 4096;
    const size_t rowK = (size_t)(b * 128 + 64 + h) * 4096;
#pragma unroll
    for (int j = 0; j < 4; ++j) {
      const int t = t0 + j * 16 + l15;
      const float ek = expf(accK[j][r] + bkv);
      const float ev = accV[j][r] + bvv;
      XT[rowKV + t] = (f16)(ek * ev);
      XT[rowK + t] = (f16)ek;
    }
  }
}

// ---------------- k2_big: Yt = sigQ * (ew@num^T)/(ew@den^T), fused ----------------
// R4-proven compute geometry (K-split-4, wave tile 128x64, BK=128, LDS merge,
// XOR-16 swizzle, in-reg num/den pairing) with A (ew) moved OFF the gld16 DMA
// path: coalesced dwordx4 global->VGPR (pre-swizzled source) + linear
// ds_write_b128, T14 split (load 1 iter early, write after post-compute
// barrier). B (XT) stays on gld16. DMA bytes/CU halve (2MB -> 1MB).
// The AWRITE data-dependency acts as the counted vmcnt (drains exactly
// through B(t+1)); no explicit vmcnt in the main loop.
__global__ __launch_bounds__(512) void k2_big(const f16* __restrict__ A,
                                              const f16* __restrict__ Bm,
                                              const f16* __restrict__ sigQ,
                                              f16* __restrict__ Yt) {
  __shared__ alignas(16) f16 smem[4][16384];  // [0][1]=A dbuf, [2][3]=B dbuf (128KB)
  const int tid = threadIdx.x;
  const int wave = tid >> 6, lane = tid & 63;
  const int kq = wave >> 1;  // K-quarter 0..3 of each BK=128 tile
  const int ws = wave & 1;   // 32-col half within num (and den)
  const int bid = blockIdx.x;
  const int b = (bid >> 3) & 7;
  const int m0 = ((bid & 7) + 8 * (bid >> 6)) * 128;  // same-m blocks share XCD
  const f16* Bb = Bm + (size_t)(b * 128) * 4096;

  // B staging map (R4-verbatim): pre-swizzled source, linear LDS dest
  const int srow = tid >> 4;   // 0..31
  const int sc16 = tid & 15;   // chunk 0..15
  const int gcol = (sc16 ^ (srow & 15)) * 8;

  // A manual-staging map: d = u*512+tid -> row d>>4, chunk d&15, pre-swizzled src
  int aRow[4], aCol[4];
#pragma unroll
  for (int u = 0; u < 4; ++u) {
    int d = u * 512 + tid;
    aRow[u] = d >> 4;
    aCol[u] = ((d & 15) ^ ((d >> 4) & 15)) * 8;
  }

  f32x16 acc[4][2];
#pragma unroll
  for (int i = 0; i < 4; ++i)
#pragma unroll
    for (int j = 0; j < 2; ++j)
#pragma unroll
      for (int r = 0; r < 16; ++r) acc[i][j][r] = 0.f;

  f16x8 arE[4], arO[4];

  const int l31 = lane & 31, l15 = lane & 15, lhi = lane >> 5;
  const int c0 = kq * 4 + lhi;
  const int cx0 = (c0 ^ l15) * 8;
  const int cx1 = ((c0 + 2) ^ l15) * 8;

#define SB0 __builtin_amdgcn_sched_barrier(0)

#define K2_ALOAD(dst, T)                                                        \
  do {                                                                          \
    _Pragma("unroll") for (int u = 0; u < 4; ++u)                               \
        dst[u] = *(const f16x8*)(A + (size_t)(m0 + aRow[u]) * 4096 +            \
                                 (size_t)(T) * 128 + aCol[u]);                  \
  } while (0)

#define K2_AWRITE(c, src)                                                       \
  do {                                                                          \
    _Pragma("unroll") for (int u = 0; u < 4; ++u)                               \
        *(f16x8*)&smem[c][(u * 512 + tid) * 8] = src[u];                        \
  } while (0)

#define K2_BSTAGE(c, T)                                                         \
  do {                                                                          \
    _Pragma("unroll") for (int q = 0; q < 4; ++q) {                             \
      int r = q * 32 + srow;                                                    \
      gld16(Bb + (size_t)r * 4096 + (size_t)(T) * 128 + gcol,                   \
            &smem[2 + (c)][r * 128 + sc16 * 8]);                                \
    }                                                                           \
  } while (0)

#define K2_COMPUTE(c)                                                           \
  do {                                                                          \
    const f16* pA = smem[c];                                                    \
    const f16* pB = smem[2 + (c)];                                              \
    f16x8 a0[4], a1[4], b0[2], b1[2];                                           \
    _Pragma("unroll") for (int i = 0; i < 4; ++i)                               \
        a0[i] = *(const f16x8*)&pA[(i * 32 + l31) * 128 + cx0];                 \
    _Pragma("unroll") for (int j = 0; j < 2; ++j)                               \
        b0[j] = *(const f16x8*)&pB[(j * 64 + ws * 32 + l31) * 128 + cx0];       \
    _Pragma("unroll") for (int i = 0; i < 4; ++i)                               \
        a1[i] = *(const f16x8*)&pA[(i * 32 + l31) * 128 + cx1];                 \
    _Pragma("unroll") for (int j = 0; j < 2; ++j)                               \
        b1[j] = *(const f16x8*)&pB[(j * 64 + ws * 32 + l31) * 128 + cx1];       \
    __builtin_amdgcn_s_setprio(1);                                              \
    _Pragma("unroll") for (int i = 0; i < 4; ++i)                               \
        _Pragma("unroll") for (int j = 0; j < 2; ++j)                           \
            acc[i][j] = MFMA32(a0[i], b0[j], acc[i][j]);                        \
    _Pragma("unroll") for (int i = 0; i < 4; ++i)                               \
        _Pragma("unroll") for (int j = 0; j < 2; ++j)                           \
            acc[i][j] = MFMA32(a1[i], b1[j], acc[i][j]);                        \
    __builtin_amdgcn_s_setprio(0);                                              \
  } while (0)

// body: compute t; barrier; write A(t+2); DMA B(t+2); load A(t+3); lgkm; barrier
#define K2_BODY(T, CUR, NXT, DOLOAD)                                            \
  do {                                                                          \
    K2_COMPUTE((T) & 1);                                                        \
    SB0;                                                                        \
    __builtin_amdgcn_s_barrier();                                               \
    SB0;                                                                        \
    K2_AWRITE((T) & 1, CUR); /* implicit vmcnt: drains B(t+1) too (counted) */  \
    K2_BSTAGE((T) & 1, (T) + 2);                                                \
    if (DOLOAD) K2_ALOAD(NXT, (T) + 3);                                         \
    asm volatile("s_waitcnt lgkmcnt(0)" ::: "memory");                          \
    SB0;                                                                        \
    __builtin_amdgcn_s_barrier();                                               \
    SB0;                                                                        \
  } while (0)

  // prologue: tiles 0,1 staged (A written, B0 drained by arO's implicit wait)
  K2_ALOAD(arE, 0);
  K2_BSTAGE(0, 0);
  K2_AWRITE(0, arE);
  K2_ALOAD(arO, 1);
  K2_BSTAGE(1, 1);
  K2_AWRITE(1, arO);  // implicit wait on A(1) drains B(0)
  K2_ALOAD(arE, 2);
  asm volatile("s_waitcnt lgkmcnt(0)" ::: "memory");
  SB0;
  __builtin_amdgcn_s_barrier();
  SB0;

  for (int t = 0; t < 28; t += 2) {
    K2_BODY(t, arE, arO, 1);
    K2_BODY(t + 1, arO, arE, 1);
  }
  K2_BODY(28, arE, arO, 1);  // loads A(31) into arO
  K2_BODY(29, arO, arE, 0);  // writes A(31), stages B(31); nothing to load
  // t = 30
  K2_COMPUTE(0);
  SB0;
  __builtin_amdgcn_s_barrier();
  SB0;
  asm volatile("s_waitcnt vmcnt(0)" ::: "memory");  // B(31) landed (all waves)
  SB0;
  __builtin_amdgcn_s_barrier();
  SB0;
  // t = 31
  K2_COMPUTE(1);
#undef K2_BODY
#undef K2_COMPUTE
#undef K2_BSTAGE
#undef K2_AWRITE
#undef K2_ALOAD

  // ---- tree-merge of 4 K-partials through LDS (R4-verbatim) ----
  __syncthreads();
  float* scr = (float*)smem;
  const int rit0 = 4 * lhi;
#define MRG_ADDR(reg, i, j, r) \
  ((reg) * 16384 + ((i) * 32 + ((r) & 3) + 8 * ((r) >> 2) + rit0) * 128 + (j) * 64 + ws * 32 + l31)
  if (kq & 1) {  // kq 1,3 write regions 0,1
#pragma unroll
    for (int i = 0; i < 4; ++i)
#pragma unroll
      for (int j = 0; j < 2; ++j)
#pragma unroll
        for (int r = 0; r < 16; ++r) scr[MRG_ADDR(kq >> 1, i, j, r)] = acc[i][j][r];
  }
  __syncthreads();
  if (!(kq & 1)) {  // kq 0,2 accumulate
#pragma unroll
    for (int i = 0; i < 4; ++i)
#pragma unroll
      for (int j = 0; j < 2; ++j)
#pragma unroll
        for (int r = 0; r < 16; ++r) acc[i][j][r] += scr[MRG_ADDR(kq >> 1, i, j, r)];
  }
  __syncthreads();
  if (kq == 2) {  // write merged upper half to region 0
#pragma unroll
    for (int i = 0; i < 4; ++i)
#pragma unroll
      for (int j = 0; j < 2; ++j)
#pragma unroll
        for (int r = 0; r < 16; ++r) scr[MRG_ADDR(0, i, j, r)] = acc[i][j][r];
  }
  __syncthreads();
  if (kq == 0) {  // final sum + fused epilogue
#pragma unroll
    for (int i = 0; i < 4; ++i)
#pragma unroll
      for (int j = 0; j < 2; ++j)
#pragma unroll
        for (int r = 0; r < 16; ++r) acc[i][j][r] += scr[MRG_ADDR(0, i, j, r)];
    const int h = ws * 32 + l31;
#pragma unroll
    for (int i = 0; i < 4; ++i)
#pragma unroll
      for (int r = 0; r < 16; ++r) {
        const int trow = m0 + i * 32 + (r & 3) + 8 * (r >> 2) + rit0;
        const size_t mrow = (size_t)b * 4096 + trow;
        const float sq = (float)sigQ[mrow * 64 + h];
        Yt[mrow * 64 + h] = (f16)(sq * acc[i][0][r] / acc[i][1][r]);
      }
  }
#undef MRG_ADDR
#undef SB0
}

// ---------------- k4_out: out[m][d] = Yt @ wp^T + bp (f32 out) ----------------
__global__ __launch_bounds__(256) void k4_out(const f16* __restrict__ Yt,
                                              const f16* __restrict__ wpb,
                                              const float* __restrict__ bp,
                                              float* __restrict__ out) {
  __shared__ alignas(16) f16 sA[128 * 64];
  __shared__ alignas(16) f16 sB[128 * 64];
  const int tid = threadIdx.x;
  const int wave = tid >> 6, lane = tid & 63;
  const int m0 = blockIdx.x * 128;  // 256
  const int n0 = blockIdx.y * 128;  // 4
  const int wm = (wave >> 1) * 64;
  const int wn = (wave & 1) * 64;
  const int l15 = lane & 15;
  const int sc8 = tid & 7;
  const int scol = (sc8 ^ ((tid >> 3) & 7)) * 8;

#pragma unroll
  for (int q = 0; q < 4; ++q) {
    int r = q * 32 + (tid >> 3);
    gld16(Yt + (size_t)(m0 + r) * 64 + scol, &sA[r * 64 + sc8 * 8]);
    gld16(wpb + (size_t)(n0 + r) * 64 + scol, &sB[r * 64 + sc8 * 8]);
  }
  __syncthreads();

  f32x4 acc[4][4];
#pragma unroll
  for (int i = 0; i < 4; ++i)
#pragma unroll
    for (int j = 0; j < 4; ++j) acc[i][j] = (f32x4){0.f, 0.f, 0.f, 0.f};

#pragma unroll
  for (int kk = 0; kk < 2; ++kk) {
    const int c = kk * 4 + (lane >> 4);
    f16x8 af[4], bfr[4];
#pragma unroll
    for (int i = 0; i < 4; ++i) {
      const int r = wm + i * 16 + l15;
      af[i] = *(const f16x8*)&sA[r * 64 + ((c ^ (r & 7)) * 8)];
    }
#pragma unroll
    for (int j = 0; j < 4; ++j) {
      const int r = wn + j * 16 + l15;
      bfr[j] = *(const f16x8*)&sB[r * 64 + ((c ^ (r & 7)) * 8)];
    }
#pragma unroll
    for (int i = 0; i < 4; ++i)
#pragma unroll
      for (int j = 0; j < 4; ++j) acc[i][j] = MFMA16(af[i], bfr[j], acc[i][j]);
  }

#pragma unroll
  for (int i = 0; i < 4; ++i) {
    const int row = m0 + wm + i * 16 + (lane >> 4) * 4;
#pragma unroll
    for (int j = 0; j < 4; ++j) {
      const int col = n0 + wn + j * 16 + l15;
      const float bpv = bp[col];
#pragma unroll
      for (int r = 0; r < 4; ++r)
        out[(size_t)(row + r) * 512 + col] = acc[i][j][r] + bpv;
    }
  }
}

extern "C" void kernel_launch(void* const* d_in, const int* in_sizes, int n_in,
                              void* d_out, int out_size, void* d_ws, size_t ws_size,
                              hipStream_t stream) {
  const float* x = (const float*)d_in[0];
  const float* wq = (const float*)d_in[1];
  const float* bq = (const float*)d_in[2];
  const float* wk = (const float*)d_in[3];
  const float* bk = (const float*)d_in[4];
  const float* wv = (const float*)d_in[5];
  const float* bv = (const float*)d_in[6];
  const float* wp = (const float*)d_in[7];
  const float* bp = (const float*)d_in[8];
  const float* wbias = (const float*)d_in[9];
  float* out = (float*)d_out;

  char* ws = (char*)d_ws;
  f16* ew = (f16*)(ws);                  // 33,554,432 B
  f16* XT = (f16*)(ws + 33554432);       //  8,388,608 B
  f16* sigQ = (f16*)(ws + 41943040);     //  4,194,304 B
  f16* Yt = (f16*)(ws + 46137344);       //  4,194,304 B
  f16* wqkvb = (f16*)(ws + 50331648);    //    196,608 B
  f16* wpb = (f16*)(ws + 50528256);      //     65,536 B (end 50,593,792)

  prep_ew<<<4096, 256, 0, stream>>>(wbias, ew);
  prep_w<<<128, 256, 0, stream>>>(wq, wk, wv, wp, wqkvb, wpb);
  k1_qkv<<<512, 256, 0, stream>>>(x, wqkvb, bq, bk, bv, sigQ, XT);
  k2_big<<<256, 512, 0, stream>>>(ew, XT, sigQ, Yt);
  k4_out<<<dim3(256, 4), 256, 0, stream>>>(Yt, wpb, bp, out);
}

// Round 10
// 95.661 us; speedup vs baseline: 2.0144x; 1.1095x over previous
//
#include <hip/hip_runtime.h>
#include <math.h>

typedef _Float16 f16;
typedef __attribute__((ext_vector_type(8))) _Float16 f16x8;
typedef __attribute__((ext_vector_type(4))) _Float16 f16x4;
typedef __attribute__((ext_vector_type(4))) float f32x4;
typedef __attribute__((ext_vector_type(16))) float f32x16;

#define MFMA16(a, b, c) __builtin_amdgcn_mfma_f32_16x16x32_f16((a), (b), (c), 0, 0, 0)
#define MFMA32(a, b, c) __builtin_amdgcn_mfma_f32_32x32x16_f16((a), (b), (c), 0, 0, 0)

__device__ __forceinline__ void gld16(const f16* g, f16* l) {
  __builtin_amdgcn_global_load_lds(
      (const __attribute__((address_space(1))) unsigned int*)g,
      (__attribute__((address_space(3))) unsigned int*)l, 16, 0, 0);
}

__device__ __forceinline__ f16x8 pack8(const float* src) {
  float4 f0 = *(const float4*)src;
  float4 f1 = *(const float4*)(src + 4);
  f16x8 v;
  v[0] = (f16)f0.x; v[1] = (f16)f0.y; v[2] = (f16)f0.z; v[3] = (f16)f0.w;
  v[4] = (f16)f1.x; v[5] = (f16)f1.y; v[6] = (f16)f1.z; v[7] = (f16)f1.w;
  return v;
}

// ---------------- prep: ew = exp(wbias) f16; blocks <128 also cast weights ----------
__global__ __launch_bounds__(256) void prep_ewpw(const float* __restrict__ wb,
                                                 f16* __restrict__ ew,
                                                 const float* __restrict__ wq,
                                                 const float* __restrict__ wk,
                                                 const float* __restrict__ wv,
                                                 const float* __restrict__ wp,
                                                 f16* __restrict__ wqkvb,
                                                 f16* __restrict__ wpb) {
  const size_t stride = (size_t)gridDim.x * 256;
  const size_t total = (size_t)4096 * 4096 / 4;
  for (size_t i = (size_t)blockIdx.x * 256 + threadIdx.x; i < total; i += stride) {
    float4 f = ((const float4*)wb)[i];
    f16x4 o;
    o.x = (f16)expf(f.x); o.y = (f16)expf(f.y);
    o.z = (f16)expf(f.z); o.w = (f16)expf(f.w);
    ((f16x4*)ew)[i] = o;
  }
  if (blockIdx.x < 128) {
    int i = blockIdx.x * 256 + threadIdx.x;  // [0, 32768)
    wqkvb[i] = (f16)wk[i];
    wqkvb[32768 + i] = (f16)wv[i];
    wqkvb[65536 + i] = (f16)wq[i];
    wpb[i] = (f16)wp[i];
  }
}

// ---------------- k1_qkv: sigQ[m][h], XT[b*128+h][t]=eK*V, XT[b*128+64+h][t]=eK --------
__global__ __launch_bounds__(256) void k1_qkv(const float* __restrict__ x,
                                              const f16* __restrict__ wqkvb,
                                              const float* __restrict__ bq,
                                              const float* __restrict__ bk,
                                              const float* __restrict__ bv,
                                              f16* __restrict__ sigQ,
                                              f16* __restrict__ XT) {
  __shared__ alignas(16) f16 sW[192 * 64];
  __shared__ alignas(16) f16 sX[64 * 64];
  const int tid = threadIdx.x;
  const int wave = tid >> 6, lane = tid & 63;
  const int m0 = blockIdx.x * 64;
  const int l15 = lane & 15;

  f32x4 accQ[4], accK[4], accV[4];
#pragma unroll
  for (int j = 0; j < 4; ++j) {
    accQ[j] = (f32x4){0.f, 0.f, 0.f, 0.f};
    accK[j] = (f32x4){0.f, 0.f, 0.f, 0.f};
    accV[j] = (f32x4){0.f, 0.f, 0.f, 0.f};
  }

  const int sc8 = tid & 7;
  const int wr8 = (tid >> 3) & 7;
  const int wcol = (sc8 ^ wr8) * 8;

  for (int ks = 0; ks < 512; ks += 64) {
#pragma unroll
    for (int q = 0; q < 6; ++q) {
      int r = q * 32 + (tid >> 3);
      gld16(wqkvb + (size_t)r * 512 + ks + wcol, &sW[r * 64 + sc8 * 8]);
    }
#pragma unroll
    for (int u = 0; u < 2; ++u) {
      int un = tid + u * 256;
      int r = un >> 3, c8 = un & 7;
      *(f16x8*)&sX[r * 64 + ((c8 ^ (r & 7)) * 8)] =
          pack8(x + (size_t)(m0 + r) * 512 + ks + c8 * 8);
    }
    __syncthreads();
#pragma unroll
    for (int kk = 0; kk < 2; ++kk) {
      const int c = kk * 4 + (lane >> 4);
      const int rK = wave * 16 + l15;
      const int rV = 64 + rK;
      f16x8 aK = *(const f16x8*)&sW[rK * 64 + ((c ^ (rK & 7)) * 8)];
      f16x8 aV = *(const f16x8*)&sW[rV * 64 + ((c ^ (rV & 7)) * 8)];
      f16x8 aQ = *(const f16x8*)&sX[rK * 64 + ((c ^ (rK & 7)) * 8)];
#pragma unroll
      for (int j = 0; j < 4; ++j) {
        const int rX = j * 16 + l15;
        const int rWq = 128 + j * 16 + l15;
        f16x8 bx = *(const f16x8*)&sX[rX * 64 + ((c ^ (rX & 7)) * 8)];
        f16x8 bw = *(const f16x8*)&sW[rWq * 64 + ((c ^ (rWq & 7)) * 8)];
        accK[j] = MFMA16(aK, bx, accK[j]);
        accV[j] = MFMA16(aV, bx, accV[j]);
        accQ[j] = MFMA16(aQ, bw, accQ[j]);
      }
    }
    __syncthreads();
  }
  const int b = m0 >> 12, t0 = m0 & 4095;
#pragma unroll
  for (int j = 0; j < 4; ++j) {
    const int h = j * 16 + l15;
    const float bqv = bq[h];
#pragma unroll
    for (int r = 0; r < 4; ++r) {
      const int m = m0 + wave * 16 + (lane >> 4) * 4 + r;
      const float v = accQ[j][r] + bqv;
      sigQ[(size_t)m * 64 + h] = (f16)(1.f / (1.f + expf(-v)));
    }
  }
#pragma unroll
  for (int r = 0; r < 4; ++r) {
    const int h = wave * 16 + (lane >> 4) * 4 + r;
    const float bkv = bk[h], bvv = bv[h];
    const size_t rowKV = (size_t)(b * 128 + h) * 4096;
    const size_t rowK = (size_t)(b * 128 + 64 + h) * 4096;
#pragma unroll
    for (int j = 0; j < 4; ++j) {
      const int t = t0 + j * 16 + l15;
      const float ek = expf(accK[j][r] + bkv);
      const float ev = accV[j][r] + bvv;
      XT[rowKV + t] = (f16)(ek * ev);
      XT[rowK + t] = (f16)ek;
    }
  }
}

// ---------------- k2_big: out = (sigQ * (ew@num^T)/(ew@den^T)) @ wp^T + bp ------------
// 1024 thr = 16 waves = 4 waves/SIMD (the occupancy lever). BM=BN=128, BK=128.
// Wave (kq = w>>2 K-quarter, wr = (w>>1)&1, wc = w&1): 64x64 tile, acc[2][2],
// num/den paired in-register. R4-proven XOR-16 both-sides swizzle + counted
// vmcnt(4) double-buffer schedule. 2-round LDS tree-merge of 4 K-quarters.
// FUSED TAIL: Yt -> LDS [128][68], wp -> LDS [512][68] (reg-preloaded), all 16
// waves run the 128x512x64 out-projection GEMM and write `out` directly.
__global__ __launch_bounds__(1024) void k2_big(const f16* __restrict__ A,
                                               const f16* __restrict__ Bm,
                                               const f16* __restrict__ sigQ,
                                               const f16* __restrict__ wpb,
                                               const float* __restrict__ bp,
                                               float* __restrict__ out) {
  __shared__ alignas(16) f16 smem[4][16384];  // A dbuf [0][1], B dbuf [2][3] (128 KB)
  const int tid = threadIdx.x;
  const int w = tid >> 6, lane = tid & 63;
  const int kq = w >> 2;          // K-quarter 0..3
  const int wr = (w >> 1) & 1;    // row half (64 rows)
  const int wc = w & 1;           // col half within num (and den)
  const int bid = blockIdx.x;
  const int b = (bid >> 3) & 7;
  const int m0 = ((bid & 7) + 8 * (bid >> 6)) * 128;  // same-m blocks share XCD
  const f16* Bb = Bm + (size_t)(b * 128) * 4096;

  // staging map: d = u*1024+tid -> row d>>4, chunk d&15, pre-swizzled source col
  int sRow[2], sCol[2];
#pragma unroll
  for (int u = 0; u < 2; ++u) {
    int d = u * 1024 + tid;
    sRow[u] = d >> 4;
    sCol[u] = ((d & 15) ^ ((d >> 4) & 15)) * 8;
  }

  f32x16 acc[2][2];
#pragma unroll
  for (int i = 0; i < 2; ++i)
#pragma unroll
    for (int j = 0; j < 2; ++j)
#pragma unroll
      for (int r = 0; r < 16; ++r) acc[i][j][r] = 0.f;

#define SB0 __builtin_amdgcn_sched_barrier(0)
#define K2_STAGE(buf, ks)                                                       \
  do {                                                                          \
    _Pragma("unroll") for (int u = 0; u < 2; ++u) {                             \
      gld16(A + (size_t)(m0 + sRow[u]) * 4096 + (ks) + sCol[u],                 \
            &smem[buf][(u * 1024 + tid) * 8]);                                  \
      gld16(Bb + (size_t)sRow[u] * 4096 + (ks) + sCol[u],                       \
            &smem[2 + (buf)][(u * 1024 + tid) * 8]);                            \
    }                                                                           \
  } while (0)

  K2_STAGE(0, 0);
  K2_STAGE(1, 128);
  asm volatile("s_waitcnt vmcnt(4)" ::: "memory");  // tile 0's 4 loads landed
  SB0;
  __builtin_amdgcn_s_barrier();
  SB0;

  const int l31 = lane & 31, l15 = lane & 15, lhi = lane >> 5;
  const int c0 = kq * 4 + lhi;
  const int cx0 = (c0 ^ l15) * 8;
  const int cx1 = ((c0 + 2) ^ l15) * 8;
  const int arow0 = (wr * 64 + l31) * 128;
  const int arow1 = (wr * 64 + 32 + l31) * 128;
  const int brow0 = (wc * 32 + l31) * 128;        // num (eK*V rows)
  const int brow1 = (64 + wc * 32 + l31) * 128;   // den (eK rows)

  const int nk = 32;
  for (int t = 0; t < nk; ++t) {
    const int cur = t & 1;
    const f16* pA = smem[cur];
    const f16* pB = smem[2 + cur];
    f16x8 a00 = *(const f16x8*)&pA[arow0 + cx0];
    f16x8 a10 = *(const f16x8*)&pA[arow1 + cx0];
    f16x8 b00 = *(const f16x8*)&pB[brow0 + cx0];
    f16x8 b10 = *(const f16x8*)&pB[brow1 + cx0];
    f16x8 a01 = *(const f16x8*)&pA[arow0 + cx1];
    f16x8 a11 = *(const f16x8*)&pA[arow1 + cx1];
    f16x8 b01 = *(const f16x8*)&pB[brow0 + cx1];
    f16x8 b11 = *(const f16x8*)&pB[brow1 + cx1];
    __builtin_amdgcn_s_setprio(1);
    acc[0][0] = MFMA32(a00, b00, acc[0][0]);
    acc[0][1] = MFMA32(a00, b10, acc[0][1]);
    acc[1][0] = MFMA32(a10, b00, acc[1][0]);
    acc[1][1] = MFMA32(a10, b10, acc[1][1]);
    acc[0][0] = MFMA32(a01, b01, acc[0][0]);
    acc[0][1] = MFMA32(a01, b11, acc[0][1]);
    acc[1][0] = MFMA32(a11, b01, acc[1][0]);
    acc[1][1] = MFMA32(a11, b11, acc[1][1]);
    __builtin_amdgcn_s_setprio(0);
    asm volatile("s_waitcnt lgkmcnt(0)" ::: "memory");
    SB0;
    __builtin_amdgcn_s_barrier();  // all waves done reading buf cur
    SB0;
    if (t + 2 < nk) {
      K2_STAGE(cur, (t + 2) * 128);
      asm volatile("s_waitcnt vmcnt(4)" ::: "memory");  // tile t+1 landed
    } else {
      asm volatile("s_waitcnt vmcnt(0)" ::: "memory");
    }
    SB0;
    __builtin_amdgcn_s_barrier();  // tile t+1 ready
    SB0;
  }
#undef K2_STAGE

  // preload wp into regs (hidden under the merge phase)
  f16x8 wpr[4];
#pragma unroll
  for (int u = 0; u < 4; ++u)
    wpr[u] = *(const f16x8*)(wpb + (size_t)(u * 1024 + tid) * 8);

  // ---- 2-round tree-merge of the 4 K-quarter partials (full 128 KB scratch) ----
  __syncthreads();
  float* scr = (float*)smem;
#define MADDR(reg, i, j, r) \
  ((reg) * 16384 + (((wr * 2 + wc) * 4 + (i) * 2 + (j)) << 10) + ((r) << 6) + lane)
  if (kq == 1) {
#pragma unroll
    for (int i = 0; i < 2; ++i)
#pragma unroll
      for (int j = 0; j < 2; ++j)
#pragma unroll
        for (int r = 0; r < 16; ++r) scr[MADDR(0, i, j, r)] = acc[i][j][r];
  }
  if (kq == 3) {
#pragma unroll
    for (int i = 0; i < 2; ++i)
#pragma unroll
      for (int j = 0; j < 2; ++j)
#pragma unroll
        for (int r = 0; r < 16; ++r) scr[MADDR(1, i, j, r)] = acc[i][j][r];
  }
  __syncthreads();
  if (kq == 0) {
#pragma unroll
    for (int i = 0; i < 2; ++i)
#pragma unroll
      for (int j = 0; j < 2; ++j)
#pragma unroll
        for (int r = 0; r < 16; ++r) acc[i][j][r] += scr[MADDR(0, i, j, r)];
  }
  if (kq == 2) {
#pragma unroll
    for (int i = 0; i < 2; ++i)
#pragma unroll
      for (int j = 0; j < 2; ++j)
#pragma unroll
        for (int r = 0; r < 16; ++r) acc[i][j][r] += scr[MADDR(1, i, j, r)];
  }
  __syncthreads();
  if (kq == 2) {
#pragma unroll
    for (int i = 0; i < 2; ++i)
#pragma unroll
      for (int j = 0; j < 2; ++j)
#pragma unroll
        for (int r = 0; r < 16; ++r) scr[MADDR(0, i, j, r)] = acc[i][j][r];
  }
  __syncthreads();
  if (kq == 0) {
#pragma unroll
    for (int i = 0; i < 2; ++i)
#pragma unroll
      for (int j = 0; j < 2; ++j)
#pragma unroll
        for (int r = 0; r < 16; ++r) acc[i][j][r] += scr[MADDR(0, i, j, r)];
  }
#undef MADDR
  __syncthreads();  // all scratch reads complete; LDS free for tail reuse

  // ---- fused tail: Yt -> sYt, wp -> sWp, out-projection GEMM ----
  f16* sYt = (f16*)smem;          // [128][68] = 8704 f16
  f16* sWp = (f16*)smem + 9216;   // [512][68] = 34816 f16 (ends 44032 < 65536)
  if (kq == 0) {
#pragma unroll
    for (int i = 0; i < 2; ++i)
#pragma unroll
      for (int r = 0; r < 16; ++r) {
        const int trow = wr * 64 + i * 32 + (r & 3) + 8 * (r >> 2) + 4 * lhi;
        const int h = wc * 32 + l31;
        const size_t mrow = (size_t)b * 4096 + m0 + trow;
        const float sq = (float)sigQ[mrow * 64 + h];
        sYt[trow * 68 + h] = (f16)(sq * acc[i][0][r] / acc[i][1][r]);
      }
  }
#pragma unroll
  for (int u = 0; u < 4; ++u) {
    const int d = u * 1024 + tid;
    *(f16x8*)&sWp[(d >> 3) * 68 + (d & 7) * 8] = wpr[u];
  }
  __syncthreads();

  f32x16 oacc[4];
#pragma unroll
  for (int cb = 0; cb < 4; ++cb)
#pragma unroll
    for (int r = 0; r < 16; ++r) oacc[cb][r] = 0.f;
  const int yrow = (w & 3) * 32 + l31;
  const int dbase = (w >> 2) * 128;
#pragma unroll
  for (int c = 0; c < 4; ++c) {
    f16x8 ay = *(const f16x8*)&sYt[yrow * 68 + c * 16 + lhi * 8];
#pragma unroll
    for (int cb = 0; cb < 4; ++cb) {
      f16x8 bw = *(const f16x8*)&sWp[(dbase + cb * 32 + l31) * 68 + c * 16 + lhi * 8];
      oacc[cb] = MFMA32(ay, bw, oacc[cb]);
    }
  }
#pragma unroll
  for (int cb = 0; cb < 4; ++cb) {
    const int od = dbase + cb * 32 + l31;
    const float bpv = bp[od];
#pragma unroll
    for (int r = 0; r < 16; ++r) {
      const int orow = (w & 3) * 32 + (r & 3) + 8 * (r >> 2) + 4 * lhi;
      out[((size_t)(b * 4096 + m0 + orow)) * 512 + od] = oacc[cb][r] + bpv;
    }
  }
#undef SB0
}

extern "C" void kernel_launch(void* const* d_in, const int* in_sizes, int n_in,
                              void* d_out, int out_size, void* d_ws, size_t ws_size,
                              hipStream_t stream) {
  const float* x = (const float*)d_in[0];
  const float* wq = (const float*)d_in[1];
  const float* bq = (const float*)d_in[2];
  const float* wk = (const float*)d_in[3];
  const float* bk = (const float*)d_in[4];
  const float* wv = (const float*)d_in[5];
  const float* bv = (const float*)d_in[6];
  const float* wp = (const float*)d_in[7];
  const float* bp = (const float*)d_in[8];
  const float* wbias = (const float*)d_in[9];
  float* out = (float*)d_out;

  char* ws = (char*)d_ws;
  f16* ew = (f16*)(ws);                  // 33,554,432 B
  f16* XT = (f16*)(ws + 33554432);       //  8,388,608 B
  f16* sigQ = (f16*)(ws + 41943040);     //  4,194,304 B
  f16* wqkvb = (f16*)(ws + 46137344);    //    196,608 B
  f16* wpb = (f16*)(ws + 46333952);      //     65,536 B (end 46,399,488)

  prep_ewpw<<<4096, 256, 0, stream>>>(wbias, ew, wq, wk, wv, wp, wqkvb, wpb);
  k1_qkv<<<512, 256, 0, stream>>>(x, wqkvb, bq, bk, bv, sigQ, XT);
  k2_big<<<256, 1024, 0, stream>>>(ew, XT, sigQ, wpb, bp, out);
}

// Round 11
// 95.516 us; speedup vs baseline: 2.0175x; 1.0015x over previous
//
#include <hip/hip_runtime.h>
#include <math.h>

typedef _Float16 f16;
typedef __attribute__((ext_vector_type(8))) _Float16 f16x8;
typedef __attribute__((ext_vector_type(4))) _Float16 f16x4;
typedef __attribute__((ext_vector_type(4))) float f32x4;
typedef __attribute__((ext_vector_type(16))) float f32x16;

#define MFMA16(a, b, c) __builtin_amdgcn_mfma_f32_16x16x32_f16((a), (b), (c), 0, 0, 0)
#define MFMA32(a, b, c) __builtin_amdgcn_mfma_f32_32x32x16_f16((a), (b), (c), 0, 0, 0)

__device__ __forceinline__ void gld16(const f16* g, f16* l) {
  __builtin_amdgcn_global_load_lds(
      (const __attribute__((address_space(1))) unsigned int*)g,
      (__attribute__((address_space(3))) unsigned int*)l, 16, 0, 0);
}

__device__ __forceinline__ f16x8 pack8(const float* src) {
  float4 f0 = *(const float4*)src;
  float4 f1 = *(const float4*)(src + 4);
  f16x8 v;
  v[0] = (f16)f0.x; v[1] = (f16)f0.y; v[2] = (f16)f0.z; v[3] = (f16)f0.w;
  v[4] = (f16)f1.x; v[5] = (f16)f1.y; v[6] = (f16)f1.z; v[7] = (f16)f1.w;
  return v;
}

// ---------------- prep: ew = exp(wbias) f16; blocks <128 also cast weights ----------
__global__ __launch_bounds__(256) void prep_ewpw(const float* __restrict__ wb,
                                                 f16* __restrict__ ew,
                                                 const float* __restrict__ wq,
                                                 const float* __restrict__ wk,
                                                 const float* __restrict__ wv,
                                                 const float* __restrict__ wp,
                                                 f16* __restrict__ wqkvb,
                                                 f16* __restrict__ wpb) {
  const size_t stride = (size_t)gridDim.x * 256;
  const size_t total = (size_t)4096 * 4096 / 4;
  for (size_t i = (size_t)blockIdx.x * 256 + threadIdx.x; i < total; i += stride) {
    float4 f = ((const float4*)wb)[i];
    f16x4 o;
    o.x = (f16)expf(f.x); o.y = (f16)expf(f.y);
    o.z = (f16)expf(f.z); o.w = (f16)expf(f.w);
    ((f16x4*)ew)[i] = o;
  }
  if (blockIdx.x < 128) {
    int i = blockIdx.x * 256 + threadIdx.x;  // [0, 32768)
    wqkvb[i] = (f16)wk[i];
    wqkvb[32768 + i] = (f16)wv[i];
    wqkvb[65536 + i] = (f16)wq[i];
    wpb[i] = (f16)wp[i];
  }
}

// ---------------- k1_qkv: sigQ[m][h], XT[b*128+h][t]=eK*V, XT[b*128+64+h][t]=eK --------
__global__ __launch_bounds__(256) void k1_qkv(const float* __restrict__ x,
                                              const f16* __restrict__ wqkvb,
                                              const float* __restrict__ bq,
                                              const float* __restrict__ bk,
                                              const float* __restrict__ bv,
                                              f16* __restrict__ sigQ,
                                              f16* __restrict__ XT) {
  __shared__ alignas(16) f16 sW[192 * 64];
  __shared__ alignas(16) f16 sX[64 * 64];
  const int tid = threadIdx.x;
  const int wave = tid >> 6, lane = tid & 63;
  const int m0 = blockIdx.x * 64;
  const int l15 = lane & 15;

  f32x4 accQ[4], accK[4], accV[4];
#pragma unroll
  for (int j = 0; j < 4; ++j) {
    accQ[j] = (f32x4){0.f, 0.f, 0.f, 0.f};
    accK[j] = (f32x4){0.f, 0.f, 0.f, 0.f};
    accV[j] = (f32x4){0.f, 0.f, 0.f, 0.f};
  }

  const int sc8 = tid & 7;
  const int wr8 = (tid >> 3) & 7;
  const int wcol = (sc8 ^ wr8) * 8;

  for (int ks = 0; ks < 512; ks += 64) {
#pragma unroll
    for (int q = 0; q < 6; ++q) {
      int r = q * 32 + (tid >> 3);
      gld16(wqkvb + (size_t)r * 512 + ks + wcol, &sW[r * 64 + sc8 * 8]);
    }
#pragma unroll
    for (int u = 0; u < 2; ++u) {
      int un = tid + u * 256;
      int r = un >> 3, c8 = un & 7;
      *(f16x8*)&sX[r * 64 + ((c8 ^ (r & 7)) * 8)] =
          pack8(x + (size_t)(m0 + r) * 512 + ks + c8 * 8);
    }
    __syncthreads();
#pragma unroll
    for (int kk = 0; kk < 2; ++kk) {
      const int c = kk * 4 + (lane >> 4);
      const int rK = wave * 16 + l15;
      const int rV = 64 + rK;
      f16x8 aK = *(const f16x8*)&sW[rK * 64 + ((c ^ (rK & 7)) * 8)];
      f16x8 aV = *(const f16x8*)&sW[rV * 64 + ((c ^ (rV & 7)) * 8)];
      f16x8 aQ = *(const f16x8*)&sX[rK * 64 + ((c ^ (rK & 7)) * 8)];
#pragma unroll
      for (int j = 0; j < 4; ++j) {
        const int rX = j * 16 + l15;
        const int rWq = 128 + j * 16 + l15;
        f16x8 bx = *(const f16x8*)&sX[rX * 64 + ((c ^ (rX & 7)) * 8)];
        f16x8 bw = *(const f16x8*)&sW[rWq * 64 + ((c ^ (rWq & 7)) * 8)];
        accK[j] = MFMA16(aK, bx, accK[j]);
        accV[j] = MFMA16(aV, bx, accV[j]);
        accQ[j] = MFMA16(aQ, bw, accQ[j]);
      }
    }
    __syncthreads();
  }
  const int b = m0 >> 12, t0 = m0 & 4095;
#pragma unroll
  for (int j = 0; j < 4; ++j) {
    const int h = j * 16 + l15;
    const float bqv = bq[h];
#pragma unroll
    for (int r = 0; r < 4; ++r) {
      const int m = m0 + wave * 16 + (lane >> 4) * 4 + r;
      const float v = accQ[j][r] + bqv;
      sigQ[(size_t)m * 64 + h] = (f16)(1.f / (1.f + expf(-v)));
    }
  }
#pragma unroll
  for (int r = 0; r < 4; ++r) {
    const int h = wave * 16 + (lane >> 4) * 4 + r;
    const float bkv = bk[h], bvv = bv[h];
    const size_t rowKV = (size_t)(b * 128 + h) * 4096;
    const size_t rowK = (size_t)(b * 128 + 64 + h) * 4096;
#pragma unroll
    for (int j = 0; j < 4; ++j) {
      const int t = t0 + j * 16 + l15;
      const float ek = expf(accK[j][r] + bkv);
      const float ev = accV[j][r] + bvv;
      XT[rowKV + t] = (f16)(ek * ev);
      XT[rowK + t] = (f16)ek;
    }
  }
}

// ---------------- k2_big: out = (sigQ * (ew@num^T)/(ew@den^T)) @ wp^T + bp ------------
// Fine-phase T3/T4 schedule: BK=64, TRI-buffered LDS (3 x 32KB), 2 phases per
// K-tile, each {6 ds_read frags, issue 2 gld16 of tile t+2, barrier,
// lgkmcnt(0), setprio + 8 MFMA16, barrier}; vmcnt(4) counted once per tile
// (never 0 mid-loop). 8 waves, wave tile 64x32 (16 num + 16 den cols,
// full-K accumulation -> NO merge phase; num/den in-register).
// [64][128]-packed XOR-16 swizzle (R7/R10-proven, 0 conflicts). XCD map.
// FUSED TAIL (R10 structure at 8 waves): Yt -> LDS [128][68], wp -> [512][68],
// out-projection GEMM writes `out` directly.
__global__ __launch_bounds__(512) void k2_big(const f16* __restrict__ A,
                                              const f16* __restrict__ Bm,
                                              const f16* __restrict__ sigQ,
                                              const f16* __restrict__ wpb,
                                              const float* __restrict__ bp,
                                              float* __restrict__ out) {
  __shared__ alignas(16) f16 smem[3 * 16384];  // buf k: A [64][128] @k*16384, B @+8192
  const int tid = threadIdx.x;
  const int w = tid >> 6, lane = tid & 63;
  const int wm6 = w >> 2;         // M half (64 rows): wm = wm6*64
  const int wn = w & 3;           // N quarter: cols wn*16 (num) / 64+wn*16 (den)
  const int bid = blockIdx.x;
  const int b = (bid >> 3) & 7;
  const int m0 = ((bid & 7) + 8 * (bid >> 6)) * 128;  // same-m blocks share XCD
  const f16* Bb = Bm + (size_t)(b * 128) * 4096;

  const int l31 = lane & 31, l15 = lane & 15, lhi = lane >> 5;
  const int hi4 = (lane >> 4) & 3;

  // staging map (pre-swizzled source, linear LDS dest): d = u*512+tid in [0,1024)
  int sRow[2], sCol[2];
#pragma unroll
  for (int u = 0; u < 2; ++u) {
    int d = u * 512 + tid;
    int lrow = d >> 4, cc = d & 15;
    int oc = cc ^ (lrow & 15);
    sRow[u] = lrow + 64 * (oc >> 3);   // source row in [0,128)
    sCol[u] = (oc & 7) * 8;            // source k-offset in [0,64)
  }

  f32x4 accN[4], accD[4];
#pragma unroll
  for (int i = 0; i < 4; ++i) {
    accN[i] = (f32x4){0.f, 0.f, 0.f, 0.f};
    accD[i] = (f32x4){0.f, 0.f, 0.f, 0.f};
  }

#define SB0 __builtin_amdgcn_sched_barrier(0)
#define K2_STAGE_U(bb, ks, u)                                                  \
  do {                                                                         \
    gld16(A + (size_t)(m0 + sRow[u]) * 4096 + (ks) + sCol[u],                  \
          &smem[(bb) + ((u) * 512 + tid) * 8]);                                \
    gld16(Bb + (size_t)sRow[u] * 4096 + (ks) + sCol[u],                        \
          &smem[(bb) + 8192 + ((u) * 512 + tid) * 8]);                         \
  } while (0)

  // frag addresses (constant per thread): A rows wm+i*16+l15, B rows wn*16+l15 (+64 den)
  const int am8 = wm6 * 8;
  const int bprow = (wn * 16 + l15) * 128;

#define K2_PHASE(bb, kh, bb2, ks2, DOSTAGE, VMC)                               \
  do {                                                                         \
    const f16* pA = &smem[bb];                                                 \
    const f16* pB = &smem[(bb) + 8192];                                        \
    const int c = (kh) * 4 + hi4;                                              \
    f16x8 af0 = *(const f16x8*)&pA[(0 * 16 + l15) * 128 + (((c + am8) ^ l15) * 8)]; \
    f16x8 af1 = *(const f16x8*)&pA[(1 * 16 + l15) * 128 + (((c + am8) ^ l15) * 8)]; \
    f16x8 af2 = *(const f16x8*)&pA[(2 * 16 + l15) * 128 + (((c + am8) ^ l15) * 8)]; \
    f16x8 af3 = *(const f16x8*)&pA[(3 * 16 + l15) * 128 + (((c + am8) ^ l15) * 8)]; \
    f16x8 bn = *(const f16x8*)&pB[bprow + ((c ^ l15) * 8)];                    \
    f16x8 bd = *(const f16x8*)&pB[bprow + (((c + 8) ^ l15) * 8)];              \
    if (DOSTAGE) K2_STAGE_U(bb2, ks2, kh);                                     \
    SB0;                                                                       \
    __builtin_amdgcn_s_barrier();                                              \
    SB0;                                                                       \
    asm volatile("s_waitcnt lgkmcnt(0)" ::: "memory");                         \
    SB0;                                                                       \
    __builtin_amdgcn_s_setprio(1);                                             \
    accN[0] = MFMA16(af0, bn, accN[0]); accD[0] = MFMA16(af0, bd, accD[0]);    \
    accN[1] = MFMA16(af1, bn, accN[1]); accD[1] = MFMA16(af1, bd, accD[1]);    \
    accN[2] = MFMA16(af2, bn, accN[2]); accD[2] = MFMA16(af2, bd, accD[2]);    \
    accN[3] = MFMA16(af3, bn, accN[3]); accD[3] = MFMA16(af3, bd, accD[3]);    \
    __builtin_amdgcn_s_setprio(0);                                             \
    if ((VMC) == 4) asm volatile("s_waitcnt vmcnt(4)" ::: "memory");           \
    if ((VMC) == 0) asm volatile("s_waitcnt vmcnt(0)" ::: "memory");           \
    SB0;                                                                       \
    __builtin_amdgcn_s_barrier();                                              \
    SB0;                                                                       \
  } while (0)

  // prologue: tiles 0 -> buf0, 1 -> buf1 (4 gld16 each)
  K2_STAGE_U(0, 0, 0);
  K2_STAGE_U(0, 0, 1);
  K2_STAGE_U(16384, 64, 0);
  K2_STAGE_U(16384, 64, 1);
  asm volatile("s_waitcnt vmcnt(4)" ::: "memory");  // tile 0 landed
  SB0;
  __builtin_amdgcn_s_barrier();
  SB0;

  const int nk = 64;
  int bo = 0;
  for (int t = 0; t < nk - 2; ++t) {
    int bb2 = bo + 32768;
    if (bb2 >= 49152) bb2 -= 49152;
    const int ks2 = (t + 2) * 64;
    K2_PHASE(bo, 0, bb2, ks2, 1, -1);
    K2_PHASE(bo, 1, bb2, ks2, 1, 4);   // t+1 landed; only t+2's 4 outstanding
    bo += 16384;
    if (bo == 49152) bo = 0;
  }
  // t = nk-2: no stage; drain tile nk-1
  K2_PHASE(bo, 0, 0, 0, 0, -1);
  K2_PHASE(bo, 1, 0, 0, 0, 0);
  bo += 16384;
  if (bo == 49152) bo = 0;
  // t = nk-1: compute only
  K2_PHASE(bo, 0, 0, 0, 0, -1);
  K2_PHASE(bo, 1, 0, 0, 0, -1);
#undef K2_PHASE
#undef K2_STAGE_U

  // ---- fused tail: Yt -> sYt [128][68], wp -> sWp [512][68], out-projection ----
  __syncthreads();
  f16* sYt = smem;           // 8704 f16
  f16* sWp = smem + 8704;    // 34816 f16 (ends 43520 < 49152)
  const int wm = wm6 * 64;
#pragma unroll
  for (int i = 0; i < 4; ++i) {
#pragma unroll
    for (int r = 0; r < 4; ++r) {
      const int tr = wm + i * 16 + (lane >> 4) * 4 + r;
      const int h = wn * 16 + l15;
      const size_t mrow = (size_t)b * 4096 + m0 + tr;
      const float sq = (float)sigQ[mrow * 64 + h];
      sYt[tr * 68 + h] = (f16)(sq * accN[i][r] / accD[i][r]);
    }
  }
#pragma unroll
  for (int u = 0; u < 8; ++u) {
    const int d = u * 512 + tid;
    f16x8 v = *(const f16x8*)(wpb + (size_t)d * 8);
    *(f16x8*)&sWp[(d >> 3) * 68 + (d & 7) * 8] = v;
  }
  __syncthreads();

  f32x16 oacc[8];
#pragma unroll
  for (int cb = 0; cb < 8; ++cb)
#pragma unroll
    for (int r = 0; r < 16; ++r) oacc[cb][r] = 0.f;
  const int yr = (w & 3) * 32 + l31;
  const int dbase = (w >> 2) * 256;
#pragma unroll
  for (int c = 0; c < 4; ++c) {
    f16x8 ay = *(const f16x8*)&sYt[yr * 68 + c * 16 + lhi * 8];
#pragma unroll
    for (int cb = 0; cb < 8; ++cb) {
      f16x8 bw = *(const f16x8*)&sWp[(dbase + cb * 32 + l31) * 68 + c * 16 + lhi * 8];
      oacc[cb] = MFMA32(ay, bw, oacc[cb]);
    }
  }
#pragma unroll
  for (int cb = 0; cb < 8; ++cb) {
    const int od = dbase + cb * 32 + l31;
    const float bpv = bp[od];
#pragma unroll
    for (int r = 0; r < 16; ++r) {
      const int orow = (w & 3) * 32 + (r & 3) + 8 * (r >> 2) + 4 * lhi;
      out[((size_t)(b * 4096 + m0 + orow)) * 512 + od] = oacc[cb][r] + bpv;
    }
  }
#undef SB0
}

extern "C" void kernel_launch(void* const* d_in, const int* in_sizes, int n_in,
                              void* d_out, int out_size, void* d_ws, size_t ws_size,
                              hipStream_t stream) {
  const float* x = (const float*)d_in[0];
  const float* wq = (const float*)d_in[1];
  const float* bq = (const float*)d_in[2];
  const float* wk = (const float*)d_in[3];
  const float* bk = (const float*)d_in[4];
  const float* wv = (const float*)d_in[5];
  const float* bv = (const float*)d_in[6];
  const float* wp = (const float*)d_in[7];
  const float* bp = (const float*)d_in[8];
  const float* wbias = (const float*)d_in[9];
  float* out = (float*)d_out;

  char* ws = (char*)d_ws;
  f16* ew = (f16*)(ws);                  // 33,554,432 B
  f16* XT = (f16*)(ws + 33554432);       //  8,388,608 B
  f16* sigQ = (f16*)(ws + 41943040);     //  4,194,304 B
  f16* wqkvb = (f16*)(ws + 46137344);    //    196,608 B
  f16* wpb = (f16*)(ws + 46333952);      //     65,536 B (end 46,399,488)

  prep_ewpw<<<4096, 256, 0, stream>>>(wbias, ew, wq, wk, wv, wp, wqkvb, wpb);
  k1_qkv<<<512, 256, 0, stream>>>(x, wqkvb, bq, bk, bv, sigQ, XT);
  k2_big<<<256, 512, 0, stream>>>(ew, XT, sigQ, wpb, bp, out);
}